// Round 4
// baseline (274.652 us; speedup 1.0000x reference)
//
#include <hip/hip_runtime.h>

// RecursiveNN, perfect binary tree, 8192 leaves, EMBED=512.
// LEVEL-MAJOR H layout: level h stored as dense [M_h][512] at row offset
// roff(h) = 16384 - 2^(14-h). Children of (h,m) are (h-1,2m),(h-1,2m+1), so
// level h's GEMM input [M][1024] is EXACTLY the previous level's buffer —
// no gather, no tree indexing in hot loops. Post-order node id:
// idx(h,m) = ((m+1)<<(h+1)) - 2 - popc(m).
// Numerics: fp16 hi+lo split H and W, 3-term MFMA (hh,hl,lh) => fp32-level.
//
// SYNC LESSON (r1): cooperative grid.sync costs ~50us PER SYNC on 8-XCD
// MI355X (16 syncs -> 900us). Kernel boundaries are the cheap sync.
// LATENCY LESSON (r2): small grids + direct-from-L2 B loads in the MFMA dep
// chain + few waves/CU => latency-bound collapse. Keep >=256 blocks,
// 64x64 tiles, 256-thr blocks, 2-3 blocks/CU.
// TILE LESSON (r3): BM=128/512-thr/1-block-per-CU also regresses (+21us).
// The r0 GEMM config is a real local optimum; do not perturb it.
//
// r4 (this): fuse the output projection into producers, delete out_kernel:
//  - init_out pre-fills out[node][c] = bP[c] (tiny, replaces the launch).
//  - packleaf: wave holds the full leaf row -> full dot + DIRECT store.
//  - GEMM epilogues: per-block partial dot over the block's cols
//    (gemm_lvl: via reused Red LDS; splitk: from registers), shuffle-reduce
//    within the row's lanes, one atomicAdd per (row,class) per block.
// Saves out_kernel's 32MB re-read + its work; H math byte-identical to r0;
// projection now uses pre-quantization fp32 x (error strictly decreases).

#define EMBED 512
#define K2    1024
#define WOFF  (EMBED * K2)

typedef _Float16 half8 __attribute__((ext_vector_type(8)));
typedef float    floatx4 __attribute__((ext_vector_type(4)));

__device__ __forceinline__ float relu_f(float x) { return fmaxf(x, 0.0f); }

#define GLDS16(gp, lp)                                                        \
    __builtin_amdgcn_global_load_lds(                                         \
        (const __attribute__((address_space(1))) void*)(gp),                  \
        (__attribute__((address_space(3))) void*)(lp), 16, 0, 0)

#define MFMA16(a, b, c) __builtin_amdgcn_mfma_f32_16x16x32_f16(a, b, c, 0, 0, 0)

// ---------------------------------------------------------------------------
// init: out[node][c] = bP[c] for all nodes (GEMM levels atomically add partial
// dots on top; packleaf overwrites leaf entries with complete dots).
__global__ __launch_bounds__(256)
void init_out(const float* __restrict__ bP, float* __restrict__ out, int n5)
{
    int i = blockIdx.x * 256 + threadIdx.x;
    if (i < n5) out[i] = bP[i - (i / 5) * 5];
}

// ---------------------------------------------------------------------------
// pack W into fp16 hi/lo MFMA-B fragment order + leaves into level-0 rows
// + fused leaf projection (full-row dot, direct store).
__global__ __launch_bounds__(256)
void packleaf(const float* __restrict__ W, const float* __restrict__ emb,
              const int* __restrict__ word,
              _Float16* __restrict__ Whp,       // lo at +WOFF
              _Float16* __restrict__ Hh, _Float16* __restrict__ Hl,
              const float* __restrict__ P, const float* __restrict__ bP,
              float* __restrict__ out, int nLeaves)
{
    int tid = threadIdx.x;
    int wave = tid >> 6, lane = tid & 63;

    {   // ---- pack W: 65536 jobs = 256 blocks x 256 threads
        int t = blockIdx.x * 256 + tid;
        int n = t >> 7, kc = t & 127;
        const float* src = W + (size_t)n * K2 + kc * 8;
        int s = kc >> 2, quad = kc & 3;
        int ln = (quad << 4) | (n & 15);
        size_t off = (size_t)(n >> 4) * 16384 + (size_t)s * 512 + (size_t)ln * 8;
        half8 hi, lo;
#pragma unroll
        for (int j = 0; j < 8; ++j) {
            float w = src[j];
            _Float16 h16 = (_Float16)w;
            hi[j] = h16;
            lo[j] = (_Float16)(w - (float)h16);
        }
        *(half8*)(Whp + off) = hi;
        *(half8*)(Whp + WOFF + off) = lo;
    }
    {   // ---- leaves -> level-0 rows (m-order, coalesced) + projection
#pragma unroll
        for (int i = 0; i < 8; ++i) {
            int m = blockIdx.x * 32 + wave * 8 + i;
            if (m < nLeaves) {
                int node = 2 * m - __popc(m);        // post-order leaf id
                int wd = word[node];
                const float4* src = (const float4*)(emb + (size_t)wd * EMBED) + lane * 2;
                float4 a = src[0], b = src[1];
                float v[8] = {a.x, a.y, a.z, a.w, b.x, b.y, b.z, b.w};
                float xs[8];
                half8 hi, lo;
#pragma unroll
                for (int j = 0; j < 8; ++j) {
                    float x = relu_f(v[j]);
                    xs[j] = x;
                    _Float16 h16 = (_Float16)x;
                    hi[j] = h16;
                    lo[j] = (_Float16)(x - (float)h16);
                }
                *(half8*)(Hh + (size_t)m * EMBED + lane * 8) = hi;
                *(half8*)(Hl + (size_t)m * EMBED + lane * 8) = lo;
                // ---- fused projection: full 512-dot in this wave
                float s[5];
#pragma unroll
                for (int c = 0; c < 5; ++c) {
                    const float* p = P + c * EMBED + lane * 8;
                    float4 p0 = *(const float4*)p;
                    float4 p1 = *(const float4*)(p + 4);
                    s[c] = xs[0] * p0.x + xs[1] * p0.y + xs[2] * p0.z + xs[3] * p0.w
                         + xs[4] * p1.x + xs[5] * p1.y + xs[6] * p1.z + xs[7] * p1.w;
                }
#pragma unroll
                for (int o = 32; o > 0; o >>= 1)
#pragma unroll
                    for (int c = 0; c < 5; ++c)
                        s[c] += __shfl_down(s[c], o, 64);
                if (lane == 0) {
#pragma unroll
                    for (int c = 0; c < 5; ++c)
                        out[(size_t)node * 5 + c] = s[c] + bP[c];
                }
            }
        }
    }
}

// ---------------------------------------------------------------------------
// Level GEMM for h=1,2 (M multiple of 64). Block = 64 rows x 64 cols,
// 4 waves: slice = wave>>1 (K-half = child), nh = wave&1 (col-half).
// Per BK=64 chunk: A staged via global_load_lds into fragment-order LDS
// slots -> conflict-free ds reads. B direct from packed-fragment global.
// Cross-slice fp32 reduce via Red LDS, fused bias+relu+hi/lo epilogue,
// then fused projection: final x tile staged in (reused) Red, 256 threads
// compute per-row partial dots vs P, 5 atomics per row per block.
__global__ __launch_bounds__(256)
void gemm_lvl(const _Float16* __restrict__ Ap,  // prev level base hi (lo at +hoff)
              const _Float16* __restrict__ Wp,  // Whp (lo at +WOFF)
              const float* __restrict__ bW,
              _Float16* __restrict__ Cp,        // cur level base hi (lo at +hoff)
              int hoff,
              const float* __restrict__ P, float* __restrict__ out, int lvl)
{
    __shared__ _Float16 As[16384];              // 32 KB: 32 fragment slots x 1 KB
    __shared__ float Red[4096];                 // 16 KB: 64x64 fp32

    int tid = threadIdx.x;
    int wave = tid >> 6, lane = tid & 63;
    int q = lane >> 4, r = lane & 15;
    int slice = wave >> 1, nh = wave & 1;
    int bm0 = blockIdx.x * 64, bn0 = blockIdx.y * 64;

    // Staging source (wave stages slots (slice, t, s2, hl=nh)):
    const _Float16* Asrc = Ap + (size_t)(nh ? hoff : 0)
                         + (size_t)(bm0 + r) * 1024 + slice * 512 + q * 8;

    floatx4 acc[4][2];
#pragma unroll
    for (int t = 0; t < 4; ++t)
#pragma unroll
        for (int u = 0; u < 2; ++u) acc[t][u] = (floatx4){0.f, 0.f, 0.f, 0.f};

    for (int kc = 0; kc < 8; ++kc) {
        // ---- stage 8 slots (1 KB each): slot = slice*16 + t*4 + s2*2 + nh
#pragma unroll
        for (int t = 0; t < 4; ++t)
#pragma unroll
            for (int s2 = 0; s2 < 2; ++s2) {
                const _Float16* gp = Asrc + t * (16 * 1024) + kc * 64 + s2 * 32;
                GLDS16(gp, &As[(slice * 16 + t * 4 + s2 * 2 + nh) * 512]);
            }
        __syncthreads();

#pragma unroll
        for (int s2 = 0; s2 < 2; ++s2) {
            half8 bh[2], bl[2];
#pragma unroll
            for (int u = 0; u < 2; ++u) {
                const _Float16* pb = Wp + (size_t)(blockIdx.y * 4 + nh * 2 + u) * 16384
                                   + (size_t)(slice * 16 + kc * 2 + s2) * 512 + lane * 8;
                bh[u] = *(const half8*)pb;
                bl[u] = *(const half8*)(pb + WOFF);
            }
#pragma unroll
            for (int t = 0; t < 4; ++t) {
                half8 ah = *(const half8*)&As[(slice * 16 + t * 4 + s2 * 2 + 0) * 512 + lane * 8];
                half8 al = *(const half8*)&As[(slice * 16 + t * 4 + s2 * 2 + 1) * 512 + lane * 8];
#pragma unroll
                for (int u = 0; u < 2; ++u) {
                    acc[t][u] = MFMA16(ah, bh[u], acc[t][u]);
                    acc[t][u] = MFMA16(ah, bl[u], acc[t][u]);
                    acc[t][u] = MFMA16(al, bh[u], acc[t][u]);
                }
            }
        }
        __syncthreads();
    }

    // ---- cross-slice reduce + epilogue (C/D: row = q*4+reg, col = r)
    float xv[4][2][4];
    if (slice == 1) {
#pragma unroll
        for (int t = 0; t < 4; ++t)
#pragma unroll
            for (int u = 0; u < 2; ++u)
#pragma unroll
                for (int reg = 0; reg < 4; ++reg)
                    Red[(t * 16 + q * 4 + reg) * 64 + nh * 32 + u * 16 + r]
                        = acc[t][u][reg];
    }
    __syncthreads();
    if (slice == 0) {
#pragma unroll
        for (int t = 0; t < 4; ++t)
#pragma unroll
            for (int u = 0; u < 2; ++u) {
                int col = bn0 + nh * 32 + u * 16 + r;
                float bw = bW[col];
#pragma unroll
                for (int reg = 0; reg < 4; ++reg) {
                    int ml = t * 16 + q * 4 + reg;
                    float v = acc[t][u][reg]
                            + Red[ml * 64 + nh * 32 + u * 16 + r];
                    float x = relu_f(v + bw);
                    xv[t][u][reg] = x;
                    _Float16 hi = (_Float16)x;
                    size_t o = (size_t)(bm0 + ml) * EMBED + col;
                    Cp[o] = hi;
                    Cp[o + hoff] = (_Float16)(x - (float)hi);
                }
            }
    }
    // ---- fused projection: stage x tile into (reused) Red, then per-row dots
    __syncthreads();
    if (slice == 0) {
#pragma unroll
        for (int t = 0; t < 4; ++t)
#pragma unroll
            for (int u = 0; u < 2; ++u)
#pragma unroll
            for (int reg = 0; reg < 4; ++reg)
                Red[(t * 16 + q * 4 + reg) * 64 + nh * 32 + u * 16 + r]
                    = xv[t][u][reg];
    }
    __syncthreads();
    {
        int prow = tid >> 2, seg = tid & 3;      // row 0..63, 16-col segment
        float s[5] = {0.f, 0.f, 0.f, 0.f, 0.f};
#pragma unroll
        for (int j4 = 0; j4 < 4; ++j4) {
            floatx4 xq = *(const floatx4*)&Red[prow * 64 + seg * 16 + j4 * 4];
#pragma unroll
            for (int c = 0; c < 5; ++c) {
                float4 pq = *(const float4*)&P[c * EMBED + bn0 + seg * 16 + j4 * 4];
                s[c] += xq[0] * pq.x + xq[1] * pq.y + xq[2] * pq.z + xq[3] * pq.w;
            }
        }
#pragma unroll
        for (int c = 0; c < 5; ++c) {
            s[c] += __shfl_xor(s[c], 1, 64);
            s[c] += __shfl_xor(s[c], 2, 64);
        }
        if (seg == 0) {
            int mrow = bm0 + prow;
            int node = ((mrow + 1) << (lvl + 1)) - 2 - __popc(mrow);
#pragma unroll
            for (int c = 0; c < 5; ++c)
                atomicAdd(&out[(size_t)node * 5 + c], s[c]);
        }
    }
}

// ---------------------------------------------------------------------------
// 32x32 split-K kernel (h=3,4; M multiple of 32). grid = (M/32, 16).
__global__ __launch_bounds__(256)
void gemm_splitk32(const _Float16* __restrict__ Ap, const _Float16* __restrict__ Wp,
                   const float* __restrict__ bW,
                   _Float16* __restrict__ Cp, int hoff,
                   const float* __restrict__ P, float* __restrict__ out, int lvl)
{
    __shared__ float red[4096];

    int tid = threadIdx.x;
    int wave = tid >> 6, lane = tid & 63;
    int q = lane >> 4, r = lane & 15;
    int m0 = blockIdx.x * 32, n0 = blockIdx.y * 32;

    const _Float16 *pAh[2], *pAl[2];
#pragma unroll
    for (int mi = 0; mi < 2; ++mi) {
        int m = m0 + mi * 16 + r;
        int prow = 2 * m + (wave >> 1);          // child row in prev level
        int kb = (wave & 1) * 256;               // k-offset within child
        pAh[mi] = Ap + (size_t)prow * EMBED + kb + q * 8;
        pAl[mi] = pAh[mi] + hoff;
    }
    const _Float16* pB[2];
#pragma unroll
    for (int u = 0; u < 2; ++u)
        pB[u] = Wp + (size_t)(blockIdx.y * 2 + u) * 16384
              + (size_t)(wave * 8) * 512 + lane * 8;

    floatx4 acc[2][2];
#pragma unroll
    for (int mi = 0; mi < 2; ++mi)
#pragma unroll
        for (int u = 0; u < 2; ++u) acc[mi][u] = (floatx4){0.f, 0.f, 0.f, 0.f};

#pragma unroll
    for (int s = 0; s < 8; ++s) {
        half8 ah[2], al[2], bh[2], bl[2];
#pragma unroll
        for (int mi = 0; mi < 2; ++mi) {
            ah[mi] = *(const half8*)(pAh[mi] + s * 32);
            al[mi] = *(const half8*)(pAl[mi] + s * 32);
        }
#pragma unroll
        for (int u = 0; u < 2; ++u) {
            bh[u] = *(const half8*)(pB[u] + s * 512);
            bl[u] = *(const half8*)(pB[u] + s * 512 + WOFF);
        }
#pragma unroll
        for (int mi = 0; mi < 2; ++mi)
#pragma unroll
            for (int u = 0; u < 2; ++u) {
                acc[mi][u] = MFMA16(ah[mi], bh[u], acc[mi][u]);
                acc[mi][u] = MFMA16(ah[mi], bl[u], acc[mi][u]);
                acc[mi][u] = MFMA16(al[mi], bh[u], acc[mi][u]);
            }
    }

#pragma unroll
    for (int mi = 0; mi < 2; ++mi)
#pragma unroll
        for (int u = 0; u < 2; ++u)
#pragma unroll
            for (int reg = 0; reg < 4; ++reg)
                red[wave * 1024 + (mi * 16 + q * 4 + reg) * 32 + u * 16 + r]
                    = acc[mi][u][reg];
    __syncthreads();

    int row = tid >> 3, c4 = (tid & 7) * 4;
    float xf[4];
    _Float16 hi4[4], lo4[4];
#pragma unroll
    for (int j = 0; j < 4; ++j) {
        int c = row * 32 + c4 + j;
        float v = red[c] + red[1024 + c] + red[2048 + c] + red[3072 + c];
        float x = relu_f(v + bW[n0 + c4 + j]);
        xf[j] = x;
        _Float16 hi = (_Float16)x;
        hi4[j] = hi;
        lo4[j] = (_Float16)(x - (float)hi);
    }
    size_t o = (size_t)(m0 + row) * EMBED + n0 + c4;
#pragma unroll
    for (int j = 0; j < 4; ++j) { Cp[o + j] = hi4[j]; Cp[o + hoff + j] = lo4[j]; }

    // ---- fused projection: partial dot over this thread's 4 cols
    {
        float s[5];
#pragma unroll
        for (int c = 0; c < 5; ++c) {
            float4 pq = *(const float4*)&P[c * EMBED + n0 + c4];
            s[c] = xf[0] * pq.x + xf[1] * pq.y + xf[2] * pq.z + xf[3] * pq.w;
            s[c] += __shfl_xor(s[c], 1, 64);
            s[c] += __shfl_xor(s[c], 2, 64);
            s[c] += __shfl_xor(s[c], 4, 64);
        }
        if ((tid & 7) == 0) {
            int mrow = m0 + row;
            int node = ((mrow + 1) << (lvl + 1)) - 2 - __popc(mrow);
#pragma unroll
            for (int c = 0; c < 5; ++c)
                atomicAdd(&out[(size_t)node * 5 + c], s[c]);
        }
    }
}

// ---------------------------------------------------------------------------
// 16x16 split-K kernel (h=5..13). grid = (ceil(M/16), 32).
__global__ __launch_bounds__(256)
void gemm_splitk(const _Float16* __restrict__ Ap, const _Float16* __restrict__ Wp,
                 const float* __restrict__ bW,
                 _Float16* __restrict__ Cp, int hoff, int M,
                 const float* __restrict__ P, float* __restrict__ out, int lvl)
{
    __shared__ float red[1024];

    int tid = threadIdx.x;
    int wave = tid >> 6, lane = tid & 63;
    int q = lane >> 4, r = lane & 15;
    int mt = blockIdx.x, u = blockIdx.y;

    int m = mt * 16 + r;
    if (m >= M) m = M - 1;
    int prow = 2 * m + (wave >> 1);
    int kb = (wave & 1) * 256;
    const _Float16* pAh = Ap + (size_t)prow * EMBED + kb + q * 8;
    const _Float16* pAl = pAh + hoff;
    const _Float16* pB  = Wp + (size_t)u * 16384 + (size_t)(wave * 8) * 512 + lane * 8;

    floatx4 acc = (floatx4){0.f, 0.f, 0.f, 0.f};
#pragma unroll
    for (int s = 0; s < 8; ++s) {
        half8 ah = *(const half8*)(pAh + s * 32);
        half8 al = *(const half8*)(pAl + s * 32);
        half8 bh = *(const half8*)(pB + s * 512);
        half8 bl = *(const half8*)(pB + s * 512 + WOFF);
        acc = MFMA16(ah, bh, acc);
        acc = MFMA16(ah, bl, acc);
        acc = MFMA16(al, bh, acc);
    }
#pragma unroll
    for (int reg = 0; reg < 4; ++reg)
        red[wave * 256 + (q * 4 + reg) * 16 + r] = acc[reg];
    __syncthreads();

    int row = tid >> 4, col = tid & 15;
    float v = red[row * 16 + col] + red[256 + row * 16 + col]
            + red[512 + row * 16 + col] + red[768 + row * 16 + col];
    int mm = mt * 16 + row;
    int colg = u * 16 + col;
    float x = relu_f(v + bW[colg]);
    if (mm < M) {
        _Float16 hi = (_Float16)x;
        size_t o = (size_t)mm * EMBED + colg;
        Cp[o] = hi;
        Cp[o + hoff] = (_Float16)(x - (float)hi);
    }
    // ---- fused projection: partial dot over this thread's 1 col
    {
        float s[5];
#pragma unroll
        for (int c = 0; c < 5; ++c) {
            s[c] = x * P[c * EMBED + colg];
            s[c] += __shfl_xor(s[c], 1, 64);
            s[c] += __shfl_xor(s[c], 2, 64);
            s[c] += __shfl_xor(s[c], 4, 64);
            s[c] += __shfl_xor(s[c], 8, 64);
        }
        if (col == 0 && mm < M) {
            int node = ((mm + 1) << (lvl + 1)) - 2 - __popc(mm);
#pragma unroll
            for (int c = 0; c < 5; ++c)
                atomicAdd(&out[(size_t)node * 5 + c], s[c]);
        }
    }
}

// ---------------------------------------------------------------------------
extern "C" void kernel_launch(void* const* d_in, const int* in_sizes, int n_in,
                              void* d_out, int out_size, void* d_ws, size_t ws_size,
                              hipStream_t stream)
{
    const int*   word = (const int*)d_in[1];
    const float* emb  = (const float*)d_in[4];
    const float* W    = (const float*)d_in[5];
    const float* bW   = (const float*)d_in[6];
    const float* P    = (const float*)d_in[7];
    const float* bP   = (const float*)d_in[8];
    float* out = (float*)d_out;

    int nNodes  = in_sizes[0];            // 16383
    int nLeaves = (nNodes + 1) / 2;       // 8192
    int nRows   = nNodes + 1;             // 16384

    int hoff = nRows * EMBED;             // halves between Hh and Hl
    _Float16* Hh  = (_Float16*)d_ws;
    _Float16* Hl  = Hh + hoff;
    _Float16* Whp = Hl + hoff;            // hi; lo at +WOFF

    // level row offsets: roff(h) = 16384 - 2^(14-h)
    auto roff = [&](int h) { return nRows - (1 << (14 - h)); };

    int n5 = nNodes * 5;
    init_out<<<dim3((n5 + 255) / 256), dim3(256), 0, stream>>>(bP, out, n5);

    packleaf<<<dim3(256), dim3(256), 0, stream>>>(
        W, emb, word, Whp, Hh, Hl, P, bP, out, nLeaves);

    for (int h = 1; h <= 2; ++h) {        // M = 4096, 2048
        int M = 1 << (13 - h);
        gemm_lvl<<<dim3(M / 64, 8), dim3(256), 0, stream>>>(
            Hh + (size_t)roff(h - 1) * EMBED, Whp, bW,
            Hh + (size_t)roff(h) * EMBED, hoff, P, out, h);
    }
    for (int h = 3; h <= 4; ++h) {        // M = 1024, 512
        int M = 1 << (13 - h);
        gemm_splitk32<<<dim3(M / 32, 16), dim3(256), 0, stream>>>(
            Hh + (size_t)roff(h - 1) * EMBED, Whp, bW,
            Hh + (size_t)roff(h) * EMBED, hoff, P, out, h);
    }
    for (int h = 5; h <= 13; ++h) {       // M = 256..1
        int M = 1 << (13 - h);
        gemm_splitk<<<dim3((M + 15) / 16, 32), dim3(256), 0, stream>>>(
            Hh + (size_t)roff(h - 1) * EMBED, Whp, bW,
            Hh + (size_t)roff(h) * EMBED, hoff, M, P, out, h);
    }
}

// Round 5
// 237.448 us; speedup vs baseline: 1.1567x; 1.1567x over previous
//
#include <hip/hip_runtime.h>

// RecursiveNN, perfect binary tree, 8192 leaves, EMBED=512.
// LEVEL-MAJOR H layout: level h stored as dense [M_h][512] at row offset
// roff(h) = 16384 - 2^(14-h). Children of (h,m) are (h-1,2m),(h-1,2m+1), so
// level h's GEMM input [M][1024] is EXACTLY the previous level's buffer —
// no gather, no tree indexing in hot loops. Post-order node id (final
// scatter only): idx(h,m) = ((m+1)<<(h+1)) - 2 - popc(m).
// Numerics: fp16 hi+lo split H and W, 3-term MFMA (hh,hl,lh) => fp32-level.
//
// LESSONS (r1-r4), all measured regressions vs r0's 235.5us:
//  r1: cooperative grid.sync ~50us/sync on 8 XCDs -> 1013us. Kernel
//      boundaries ARE the cheap sync.
//  r2: small grid + direct-from-L2 B in MFMA dep chain + 4 waves/CU ->
//      latency collapse (64us/level, 7% MfmaUtil).
//  r3: BM=128/512thr/1 block-per-CU -> +21us (lockstep, no overlap).
//  r4: projection fused via atomics -> +39us (32-way atomic serialization
//      per node + added VALU in every tail block).
// => r0 structure (64x64 tiles, 256thr, split-K2, 15 launches) is the
//    local optimum in structure space. Do not perturb structure.
//
// r5 (this): keep r0 EXACTLY except the gemm_lvl K-loop: double-buffered
// As (32->64KB) + counted s_waitcnt vmcnt(8) + raw s_barrier instead of
// __syncthreads' vmcnt(0) drain (T3/T4 minimum recipe). Stage latency of
// chunk kc+1 now hides under compute of chunk kc. LDS 80KB -> still
// 2 blocks/CU (= what h=1's 512-block grid yields anyway). Per-wave K
// order identical -> absmax bit-identical.

#define EMBED 512
#define K2    1024
#define WOFF  (EMBED * K2)

typedef _Float16 half8 __attribute__((ext_vector_type(8)));
typedef float    floatx4 __attribute__((ext_vector_type(4)));

__device__ __forceinline__ float relu_f(float x) { return fmaxf(x, 0.0f); }

#define GLDS16(gp, lp)                                                        \
    __builtin_amdgcn_global_load_lds(                                         \
        (const __attribute__((address_space(1))) void*)(gp),                  \
        (__attribute__((address_space(3))) void*)(lp), 16, 0, 0)

#define MFMA16(a, b, c) __builtin_amdgcn_mfma_f32_16x16x32_f16(a, b, c, 0, 0, 0)

// ---------------------------------------------------------------------------
// pack W into fp16 hi/lo MFMA-B fragment order + leaves into level-0 rows.
__global__ __launch_bounds__(256)
void packleaf(const float* __restrict__ W, const float* __restrict__ emb,
              const int* __restrict__ word,
              _Float16* __restrict__ Whp,       // lo at +WOFF
              _Float16* __restrict__ Hh, _Float16* __restrict__ Hl,
              int nLeaves)
{
    int tid = threadIdx.x;
    int wave = tid >> 6, lane = tid & 63;

    {   // ---- pack W: 65536 jobs = 256 blocks x 256 threads
        int t = blockIdx.x * 256 + tid;
        int n = t >> 7, kc = t & 127;
        const float* src = W + (size_t)n * K2 + kc * 8;
        int s = kc >> 2, quad = kc & 3;
        int ln = (quad << 4) | (n & 15);
        size_t off = (size_t)(n >> 4) * 16384 + (size_t)s * 512 + (size_t)ln * 8;
        half8 hi, lo;
#pragma unroll
        for (int j = 0; j < 8; ++j) {
            float w = src[j];
            _Float16 h16 = (_Float16)w;
            hi[j] = h16;
            lo[j] = (_Float16)(w - (float)h16);
        }
        *(half8*)(Whp + off) = hi;
        *(half8*)(Whp + WOFF + off) = lo;
    }
    {   // ---- leaves -> level-0 rows (m-order, coalesced)
#pragma unroll
        for (int i = 0; i < 8; ++i) {
            int m = blockIdx.x * 32 + wave * 8 + i;
            if (m < nLeaves) {
                int wd = word[2 * m - __popc(m)];    // post-order leaf id
                const float4* src = (const float4*)(emb + (size_t)wd * EMBED) + lane * 2;
                float4 a = src[0], b = src[1];
                float v[8] = {a.x, a.y, a.z, a.w, b.x, b.y, b.z, b.w};
                half8 hi, lo;
#pragma unroll
                for (int j = 0; j < 8; ++j) {
                    float x = relu_f(v[j]);
                    _Float16 h16 = (_Float16)x;
                    hi[j] = h16;
                    lo[j] = (_Float16)(x - (float)h16);
                }
                *(half8*)(Hh + (size_t)m * EMBED + lane * 8) = hi;
                *(half8*)(Hl + (size_t)m * EMBED + lane * 8) = lo;
            }
        }
    }
}

// ---------------------------------------------------------------------------
// Level GEMM for h=1,2 (M multiple of 64). Block = 64 rows x 64 cols,
// 4 waves: slice = wave>>1 (K-half = child), nh = wave&1 (col-half).
// r5: double-buffered As + counted vmcnt + raw barriers (see header).
// Per BK=64 chunk: A staged via global_load_lds (per-lane row gather on the
// global side) into fragment-order LDS slots -> conflict-free ds reads.
// B direct from packed-fragment global (contiguous, L2-resident).
// Cross-slice fp32 reduce via LDS, fused bias+relu+hi/lo epilogue.
__global__ __launch_bounds__(256)
void gemm_lvl(const _Float16* __restrict__ Ap,  // prev level base hi (lo at +hoff)
              const _Float16* __restrict__ Wp,  // Whp (lo at +WOFF)
              const float* __restrict__ bW,
              _Float16* __restrict__ Cp,        // cur level base hi (lo at +hoff)
              int hoff)
{
    __shared__ _Float16 As[32768];              // 64 KB: 2 bufs x 32 slots x 1 KB
    __shared__ float Red[4096];                 // 16 KB: 64x64 fp32

    int tid = threadIdx.x;
    int wave = tid >> 6, lane = tid & 63;
    int q = lane >> 4, r = lane & 15;
    int slice = wave >> 1, nh = wave & 1;
    int bm0 = blockIdx.x * 64, bn0 = blockIdx.y * 64;

    // Staging source (wave stages slots (slice, t, s2, hl=nh)):
    // A[m][1024] view == prev buffer + m*1024 halves.
    const _Float16* Asrc = Ap + (size_t)(nh ? hoff : 0)
                         + (size_t)(bm0 + r) * 1024 + slice * 512 + q * 8;

    floatx4 acc[4][2];
#pragma unroll
    for (int t = 0; t < 4; ++t)
#pragma unroll
        for (int u = 0; u < 2; ++u) acc[t][u] = (floatx4){0.f, 0.f, 0.f, 0.f};

    // ---- prologue: stage chunk 0 into buf 0 (8 slots, 1 KB each)
#pragma unroll
    for (int t = 0; t < 4; ++t)
#pragma unroll
        for (int s2 = 0; s2 < 2; ++s2) {
            const _Float16* gp = Asrc + t * (16 * 1024) + s2 * 32;
            GLDS16(gp, &As[(slice * 16 + t * 4 + s2 * 2 + nh) * 512]);
        }

    for (int kc = 0; kc < 8; ++kc) {
        int buf = kc & 1;
        // ---- prefetch chunk kc+1 into buf^1, then wait ONLY for buf's 8
        // loads (vmcnt waits the oldest (outstanding-N); stage(kc) are the
        // oldest since all older B loads were consumed by last chunk's MFMAs).
        if (kc < 7) {
#pragma unroll
            for (int t = 0; t < 4; ++t)
#pragma unroll
                for (int s2 = 0; s2 < 2; ++s2) {
                    const _Float16* gp = Asrc + t * (16 * 1024) + (kc + 1) * 64 + s2 * 32;
                    GLDS16(gp, &As[((buf ^ 1) * 32 + slice * 16 + t * 4 + s2 * 2 + nh) * 512]);
                }
            asm volatile("s_waitcnt vmcnt(8)" ::: "memory");
        } else {
            asm volatile("s_waitcnt vmcnt(0)" ::: "memory");
        }
        __builtin_amdgcn_s_barrier();           // all waves' buf staged
        __builtin_amdgcn_sched_barrier(0);      // no ds_read hoist above

#pragma unroll
        for (int s2 = 0; s2 < 2; ++s2) {
            half8 bh[2], bl[2];
#pragma unroll
            for (int u = 0; u < 2; ++u) {
                const _Float16* pb = Wp + (size_t)(blockIdx.y * 4 + nh * 2 + u) * 16384
                                   + (size_t)(slice * 16 + kc * 2 + s2) * 512 + lane * 8;
                bh[u] = *(const half8*)pb;
                bl[u] = *(const half8*)(pb + WOFF);
            }
#pragma unroll
            for (int t = 0; t < 4; ++t) {
                half8 ah = *(const half8*)&As[(buf * 32 + slice * 16 + t * 4 + s2 * 2 + 0) * 512 + lane * 8];
                half8 al = *(const half8*)&As[(buf * 32 + slice * 16 + t * 4 + s2 * 2 + 1) * 512 + lane * 8];
#pragma unroll
                for (int u = 0; u < 2; ++u) {
                    acc[t][u] = MFMA16(ah, bh[u], acc[t][u]);
                    acc[t][u] = MFMA16(ah, bl[u], acc[t][u]);
                    acc[t][u] = MFMA16(al, bh[u], acc[t][u]);
                }
            }
        }
        __builtin_amdgcn_sched_barrier(0);      // no ds_read sink below
        __builtin_amdgcn_s_barrier();           // all waves done reading buf
    }

    // ---- cross-slice reduce + epilogue (C/D: row = q*4+reg, col = r)
    if (slice == 1) {
#pragma unroll
        for (int t = 0; t < 4; ++t)
#pragma unroll
            for (int u = 0; u < 2; ++u)
#pragma unroll
                for (int reg = 0; reg < 4; ++reg)
                    Red[(t * 16 + q * 4 + reg) * 64 + nh * 32 + u * 16 + r]
                        = acc[t][u][reg];
    }
    __syncthreads();
    if (slice == 0) {
#pragma unroll
        for (int t = 0; t < 4; ++t)
#pragma unroll
            for (int u = 0; u < 2; ++u) {
                int col = bn0 + nh * 32 + u * 16 + r;
                float bw = bW[col];
#pragma unroll
                for (int reg = 0; reg < 4; ++reg) {
                    int ml = t * 16 + q * 4 + reg;
                    float v = acc[t][u][reg]
                            + Red[ml * 64 + nh * 32 + u * 16 + r];
                    float x = relu_f(v + bw);
                    _Float16 hi = (_Float16)x;
                    size_t o = (size_t)(bm0 + ml) * EMBED + col;
                    Cp[o] = hi;
                    Cp[o + hoff] = (_Float16)(x - (float)hi);
                }
            }
    }
}

// ---------------------------------------------------------------------------
// 32x32 split-K kernel (h=3,4; M multiple of 32). grid = (M/32, 16).
__global__ __launch_bounds__(256)
void gemm_splitk32(const _Float16* __restrict__ Ap, const _Float16* __restrict__ Wp,
                   const float* __restrict__ bW,
                   _Float16* __restrict__ Cp, int hoff)
{
    __shared__ float red[4096];

    int tid = threadIdx.x;
    int wave = tid >> 6, lane = tid & 63;
    int q = lane >> 4, r = lane & 15;
    int m0 = blockIdx.x * 32, n0 = blockIdx.y * 32;

    const _Float16 *pAh[2], *pAl[2];
#pragma unroll
    for (int mi = 0; mi < 2; ++mi) {
        int m = m0 + mi * 16 + r;
        int prow = 2 * m + (wave >> 1);          // child row in prev level
        int kb = (wave & 1) * 256;               // k-offset within child
        pAh[mi] = Ap + (size_t)prow * EMBED + kb + q * 8;
        pAl[mi] = pAh[mi] + hoff;
    }
    const _Float16* pB[2];
#pragma unroll
    for (int u = 0; u < 2; ++u)
        pB[u] = Wp + (size_t)(blockIdx.y * 2 + u) * 16384
              + (size_t)(wave * 8) * 512 + lane * 8;

    floatx4 acc[2][2];
#pragma unroll
    for (int mi = 0; mi < 2; ++mi)
#pragma unroll
        for (int u = 0; u < 2; ++u) acc[mi][u] = (floatx4){0.f, 0.f, 0.f, 0.f};

#pragma unroll
    for (int s = 0; s < 8; ++s) {
        half8 ah[2], al[2], bh[2], bl[2];
#pragma unroll
        for (int mi = 0; mi < 2; ++mi) {
            ah[mi] = *(const half8*)(pAh[mi] + s * 32);
            al[mi] = *(const half8*)(pAl[mi] + s * 32);
        }
#pragma unroll
        for (int u = 0; u < 2; ++u) {
            bh[u] = *(const half8*)(pB[u] + s * 512);
            bl[u] = *(const half8*)(pB[u] + s * 512 + WOFF);
        }
#pragma unroll
        for (int mi = 0; mi < 2; ++mi)
#pragma unroll
            for (int u = 0; u < 2; ++u) {
                acc[mi][u] = MFMA16(ah[mi], bh[u], acc[mi][u]);
                acc[mi][u] = MFMA16(ah[mi], bl[u], acc[mi][u]);
                acc[mi][u] = MFMA16(al[mi], bh[u], acc[mi][u]);
            }
    }

#pragma unroll
    for (int mi = 0; mi < 2; ++mi)
#pragma unroll
        for (int u = 0; u < 2; ++u)
#pragma unroll
            for (int reg = 0; reg < 4; ++reg)
                red[wave * 1024 + (mi * 16 + q * 4 + reg) * 32 + u * 16 + r]
                    = acc[mi][u][reg];
    __syncthreads();

    int row = tid >> 3, c4 = (tid & 7) * 4;
    _Float16 hi4[4], lo4[4];
#pragma unroll
    for (int j = 0; j < 4; ++j) {
        int c = row * 32 + c4 + j;
        float v = red[c] + red[1024 + c] + red[2048 + c] + red[3072 + c];
        float x = relu_f(v + bW[n0 + c4 + j]);
        _Float16 hi = (_Float16)x;
        hi4[j] = hi;
        lo4[j] = (_Float16)(x - (float)hi);
    }
    size_t o = (size_t)(m0 + row) * EMBED + n0 + c4;
#pragma unroll
    for (int j = 0; j < 4; ++j) { Cp[o + j] = hi4[j]; Cp[o + hoff + j] = lo4[j]; }
}

// ---------------------------------------------------------------------------
// 16x16 split-K kernel (h=5..13). grid = (ceil(M/16), 32).
__global__ __launch_bounds__(256)
void gemm_splitk(const _Float16* __restrict__ Ap, const _Float16* __restrict__ Wp,
                 const float* __restrict__ bW,
                 _Float16* __restrict__ Cp, int hoff, int M)
{
    __shared__ float red[1024];

    int tid = threadIdx.x;
    int wave = tid >> 6, lane = tid & 63;
    int q = lane >> 4, r = lane & 15;
    int mt = blockIdx.x, u = blockIdx.y;

    int m = mt * 16 + r;
    if (m >= M) m = M - 1;
    int prow = 2 * m + (wave >> 1);
    int kb = (wave & 1) * 256;
    const _Float16* pAh = Ap + (size_t)prow * EMBED + kb + q * 8;
    const _Float16* pAl = pAh + hoff;
    const _Float16* pB  = Wp + (size_t)u * 16384 + (size_t)(wave * 8) * 512 + lane * 8;

    floatx4 acc = (floatx4){0.f, 0.f, 0.f, 0.f};
#pragma unroll
    for (int s = 0; s < 8; ++s) {
        half8 ah = *(const half8*)(pAh + s * 32);
        half8 al = *(const half8*)(pAl + s * 32);
        half8 bh = *(const half8*)(pB + s * 512);
        half8 bl = *(const half8*)(pB + s * 512 + WOFF);
        acc = MFMA16(ah, bh, acc);
        acc = MFMA16(ah, bl, acc);
        acc = MFMA16(al, bh, acc);
    }
#pragma unroll
    for (int reg = 0; reg < 4; ++reg)
        red[wave * 256 + (q * 4 + reg) * 16 + r] = acc[reg];
    __syncthreads();

    int row = tid >> 4, col = tid & 15;
    float v = red[row * 16 + col] + red[256 + row * 16 + col]
            + red[512 + row * 16 + col] + red[768 + row * 16 + col];
    int mm = mt * 16 + row;
    if (mm < M) {
        int colg = u * 16 + col;
        float x = relu_f(v + bW[colg]);
        _Float16 hi = (_Float16)x;
        size_t o = (size_t)mm * EMBED + colg;
        Cp[o] = hi;
        Cp[o + hoff] = (_Float16)(x - (float)hi);
    }
}

// ---------------------------------------------------------------------------
// Projection: buffer row j (level-major) -> out[idx(h,m)]. Level decode:
// h = 13 - floor(log2(16383 - j)), m = j - (16384 - 2^(14-h)).
__global__ __launch_bounds__(256)
void out_kernel(const _Float16* __restrict__ Hh, const _Float16* __restrict__ Hl,
                const float* __restrict__ P, const float* __restrict__ bP,
                float* __restrict__ out, int nNodes)
{
    int t = blockIdx.x * 256 + threadIdx.x;
    int j = t >> 6, lane = t & 63;
    if (j >= nNodes) return;
    int v = nNodes - j;                         // 16383 - j >= 1
    int h = 13 - (31 - __clz(v));
    int m = j - ((nNodes + 1) - (1 << (13 - h + 1)));
    int node = ((m + 1) << (h + 1)) - 2 - __popc(m);

    half8 hv = *(const half8*)(Hh + (size_t)j * EMBED + lane * 8);
    half8 lv = *(const half8*)(Hl + (size_t)j * EMBED + lane * 8);
    float hx[8];
#pragma unroll
    for (int k = 0; k < 8; ++k) hx[k] = (float)hv[k] + (float)lv[k];
    float s[5];
#pragma unroll
    for (int c = 0; c < 5; ++c) {
        const float* p = P + c * EMBED + lane * 8;
        float4 p0 = *(const float4*)p;
        float4 p1 = *(const float4*)(p + 4);
        s[c] = hx[0] * p0.x + hx[1] * p0.y + hx[2] * p0.z + hx[3] * p0.w
             + hx[4] * p1.x + hx[5] * p1.y + hx[6] * p1.z + hx[7] * p1.w;
    }
#pragma unroll
    for (int o = 32; o > 0; o >>= 1)
#pragma unroll
        for (int c = 0; c < 5; ++c)
            s[c] += __shfl_down(s[c], o, 64);
    if (lane == 0) {
#pragma unroll
        for (int c = 0; c < 5; ++c)
            out[(size_t)node * 5 + c] = s[c] + bP[c];
    }
}

// ---------------------------------------------------------------------------
extern "C" void kernel_launch(void* const* d_in, const int* in_sizes, int n_in,
                              void* d_out, int out_size, void* d_ws, size_t ws_size,
                              hipStream_t stream)
{
    const int*   word = (const int*)d_in[1];
    const float* emb  = (const float*)d_in[4];
    const float* W    = (const float*)d_in[5];
    const float* bW   = (const float*)d_in[6];
    const float* P    = (const float*)d_in[7];
    const float* bP   = (const float*)d_in[8];
    float* out = (float*)d_out;

    int nNodes  = in_sizes[0];            // 16383
    int nLeaves = (nNodes + 1) / 2;       // 8192
    int nRows   = nNodes + 1;             // 16384

    int hoff = nRows * EMBED;             // halves between Hh and Hl
    _Float16* Hh  = (_Float16*)d_ws;
    _Float16* Hl  = Hh + hoff;
    _Float16* Whp = Hl + hoff;            // hi; lo at +WOFF

    // level row offsets: roff(h) = 16384 - 2^(14-h)
    auto roff = [&](int h) { return nRows - (1 << (14 - h)); };

    packleaf<<<dim3(256), dim3(256), 0, stream>>>(
        W, emb, word, Whp, Hh, Hl, nLeaves);

    for (int h = 1; h <= 2; ++h) {        // M = 4096, 2048
        int M = 1 << (13 - h);
        gemm_lvl<<<dim3(M / 64, 8), dim3(256), 0, stream>>>(
            Hh + (size_t)roff(h - 1) * EMBED, Whp, bW,
            Hh + (size_t)roff(h) * EMBED, hoff);
    }
    for (int h = 3; h <= 4; ++h) {        // M = 1024, 512
        int M = 1 << (13 - h);
        gemm_splitk32<<<dim3(M / 32, 16), dim3(256), 0, stream>>>(
            Hh + (size_t)roff(h - 1) * EMBED, Whp, bW,
            Hh + (size_t)roff(h) * EMBED, hoff);
    }
    for (int h = 5; h <= 13; ++h) {       // M = 256..1
        int M = 1 << (13 - h);
        gemm_splitk<<<dim3((M + 15) / 16, 32), dim3(256), 0, stream>>>(
            Hh + (size_t)roff(h - 1) * EMBED, Whp, bW,
            Hh + (size_t)roff(h) * EMBED, hoff, M);
    }
    out_kernel<<<dim3((nNodes * 64 + 255) / 256), dim3(256), 0, stream>>>(
        Hh, Hl, P, bP, out, nNodes);
}

// Round 6
// 235.547 us; speedup vs baseline: 1.1660x; 1.0081x over previous
//
#include <hip/hip_runtime.h>

// RecursiveNN, perfect binary tree, 8192 leaves, EMBED=512.
// LEVEL-MAJOR H layout: level h stored as dense [M_h][512] at row offset
// roff(h) = 16384 - 2^(14-h). Children of (h,m) are (h-1,2m),(h-1,2m+1), so
// level h's GEMM input [M][1024] is EXACTLY the previous level's buffer —
// no gather, no tree indexing in hot loops. Post-order node id (final
// scatter only): idx(h,m) = ((m+1)<<(h+1)) - 2 - popc(m).
// Numerics: fp16 hi+lo split H and W, 3-term MFMA (hh,hl,lh) => fp32-level.
//
// LESSONS (r1-r5), all vs r0's 235.5us:
//  r1: cooperative grid.sync ~50us/sync on 8 XCDs -> 1013us. Kernel
//      boundaries ARE the cheap sync.
//  r2: small grid + direct-from-L2 B in MFMA dep chain + 4 waves/CU ->
//      latency collapse (64us/level, 7% MfmaUtil).
//  r3: BM=128/512thr/1 block-per-CU -> +21us (lockstep, no overlap).
//  r4: projection fused via atomics -> +39us (32-way atomic serialization).
//  r5: explicit dbuf + counted vmcnt in gemm_lvl -> neutral (+2us):
//      at 3 blocks/CU the co-resident blocks already hide stage latency
//      (matches guide m99/m131-140). gemm_lvl is TRAFFIC-bound, not
//      stall-bound. Keep the plain __syncthreads loop.
// => structure (64x64-ish tiles, 256thr, split-K2, 15 launches) is the
//    local optimum. Remaining lever = per-kernel traffic only.
//
// r6 (this): h=1 BN 64->128 (gemm_lvl128): col-tiles 8->4 halves A re-reads
// (128->64MB), grid stays (64,4)=256 blocks, block stays 256thr/4-wave
// split-K2, A staging byte-identical. Cross-slice reduce in TWO passes
// through the same 16KB Red => LDS stays 48KB => 3 blocks/CU preserved.
// h=2 keeps BN=64 (BN=128 would drop grid to 128 blocks — r2 lesson).
// Per-wave K order and epilogue math identical => absmax bit-identical.

#define EMBED 512
#define K2    1024
#define WOFF  (EMBED * K2)

typedef _Float16 half8 __attribute__((ext_vector_type(8)));
typedef float    floatx4 __attribute__((ext_vector_type(4)));

__device__ __forceinline__ float relu_f(float x) { return fmaxf(x, 0.0f); }

#define GLDS16(gp, lp)                                                        \
    __builtin_amdgcn_global_load_lds(                                         \
        (const __attribute__((address_space(1))) void*)(gp),                  \
        (__attribute__((address_space(3))) void*)(lp), 16, 0, 0)

#define MFMA16(a, b, c) __builtin_amdgcn_mfma_f32_16x16x32_f16(a, b, c, 0, 0, 0)

// ---------------------------------------------------------------------------
// pack W into fp16 hi/lo MFMA-B fragment order + leaves into level-0 rows.
__global__ __launch_bounds__(256)
void packleaf(const float* __restrict__ W, const float* __restrict__ emb,
              const int* __restrict__ word,
              _Float16* __restrict__ Whp,       // lo at +WOFF
              _Float16* __restrict__ Hh, _Float16* __restrict__ Hl,
              int nLeaves)
{
    int tid = threadIdx.x;
    int wave = tid >> 6, lane = tid & 63;

    {   // ---- pack W: 65536 jobs = 256 blocks x 256 threads
        int t = blockIdx.x * 256 + tid;
        int n = t >> 7, kc = t & 127;
        const float* src = W + (size_t)n * K2 + kc * 8;
        int s = kc >> 2, quad = kc & 3;
        int ln = (quad << 4) | (n & 15);
        size_t off = (size_t)(n >> 4) * 16384 + (size_t)s * 512 + (size_t)ln * 8;
        half8 hi, lo;
#pragma unroll
        for (int j = 0; j < 8; ++j) {
            float w = src[j];
            _Float16 h16 = (_Float16)w;
            hi[j] = h16;
            lo[j] = (_Float16)(w - (float)h16);
        }
        *(half8*)(Whp + off) = hi;
        *(half8*)(Whp + WOFF + off) = lo;
    }
    {   // ---- leaves -> level-0 rows (m-order, coalesced)
#pragma unroll
        for (int i = 0; i < 8; ++i) {
            int m = blockIdx.x * 32 + wave * 8 + i;
            if (m < nLeaves) {
                int wd = word[2 * m - __popc(m)];    // post-order leaf id
                const float4* src = (const float4*)(emb + (size_t)wd * EMBED) + lane * 2;
                float4 a = src[0], b = src[1];
                float v[8] = {a.x, a.y, a.z, a.w, b.x, b.y, b.z, b.w};
                half8 hi, lo;
#pragma unroll
                for (int j = 0; j < 8; ++j) {
                    float x = relu_f(v[j]);
                    _Float16 h16 = (_Float16)x;
                    hi[j] = h16;
                    lo[j] = (_Float16)(x - (float)h16);
                }
                *(half8*)(Hh + (size_t)m * EMBED + lane * 8) = hi;
                *(half8*)(Hl + (size_t)m * EMBED + lane * 8) = lo;
            }
        }
    }
}

// ---------------------------------------------------------------------------
// Level GEMM, BN=64 (used for h=2). Block = 64 rows x 64 cols, 4 waves:
// slice = wave>>1 (K-half = child), nh = wave&1 (col-half). Per BK=64 chunk:
// A staged via global_load_lds into fragment-order LDS slots; B direct from
// packed-fragment global. Cross-slice fp32 reduce via Red, fused epilogue.
__global__ __launch_bounds__(256)
void gemm_lvl(const _Float16* __restrict__ Ap,  // prev level base hi (lo at +hoff)
              const _Float16* __restrict__ Wp,  // Whp (lo at +WOFF)
              const float* __restrict__ bW,
              _Float16* __restrict__ Cp,        // cur level base hi (lo at +hoff)
              int hoff)
{
    __shared__ _Float16 As[16384];              // 32 KB: 32 fragment slots x 1 KB
    __shared__ float Red[4096];                 // 16 KB: 64x64 fp32

    int tid = threadIdx.x;
    int wave = tid >> 6, lane = tid & 63;
    int q = lane >> 4, r = lane & 15;
    int slice = wave >> 1, nh = wave & 1;
    int bm0 = blockIdx.x * 64, bn0 = blockIdx.y * 64;

    const _Float16* Asrc = Ap + (size_t)(nh ? hoff : 0)
                         + (size_t)(bm0 + r) * 1024 + slice * 512 + q * 8;

    floatx4 acc[4][2];
#pragma unroll
    for (int t = 0; t < 4; ++t)
#pragma unroll
        for (int u = 0; u < 2; ++u) acc[t][u] = (floatx4){0.f, 0.f, 0.f, 0.f};

    for (int kc = 0; kc < 8; ++kc) {
        // ---- stage 8 slots (1 KB each): slot = slice*16 + t*4 + s2*2 + nh
#pragma unroll
        for (int t = 0; t < 4; ++t)
#pragma unroll
            for (int s2 = 0; s2 < 2; ++s2) {
                const _Float16* gp = Asrc + t * (16 * 1024) + kc * 64 + s2 * 32;
                GLDS16(gp, &As[(slice * 16 + t * 4 + s2 * 2 + nh) * 512]);
            }
        __syncthreads();

#pragma unroll
        for (int s2 = 0; s2 < 2; ++s2) {
            half8 bh[2], bl[2];
#pragma unroll
            for (int u = 0; u < 2; ++u) {
                const _Float16* pb = Wp + (size_t)(blockIdx.y * 4 + nh * 2 + u) * 16384
                                   + (size_t)(slice * 16 + kc * 2 + s2) * 512 + lane * 8;
                bh[u] = *(const half8*)pb;
                bl[u] = *(const half8*)(pb + WOFF);
            }
#pragma unroll
            for (int t = 0; t < 4; ++t) {
                half8 ah = *(const half8*)&As[(slice * 16 + t * 4 + s2 * 2 + 0) * 512 + lane * 8];
                half8 al = *(const half8*)&As[(slice * 16 + t * 4 + s2 * 2 + 1) * 512 + lane * 8];
#pragma unroll
                for (int u = 0; u < 2; ++u) {
                    acc[t][u] = MFMA16(ah, bh[u], acc[t][u]);
                    acc[t][u] = MFMA16(ah, bl[u], acc[t][u]);
                    acc[t][u] = MFMA16(al, bh[u], acc[t][u]);
                }
            }
        }
        __syncthreads();
    }

    // ---- cross-slice reduce + epilogue (C/D: row = q*4+reg, col = r)
    if (slice == 1) {
#pragma unroll
        for (int t = 0; t < 4; ++t)
#pragma unroll
            for (int u = 0; u < 2; ++u)
#pragma unroll
                for (int reg = 0; reg < 4; ++reg)
                    Red[(t * 16 + q * 4 + reg) * 64 + nh * 32 + u * 16 + r]
                        = acc[t][u][reg];
    }
    __syncthreads();
    if (slice == 0) {
#pragma unroll
        for (int t = 0; t < 4; ++t)
#pragma unroll
            for (int u = 0; u < 2; ++u) {
                int col = bn0 + nh * 32 + u * 16 + r;
                float bw = bW[col];
#pragma unroll
                for (int reg = 0; reg < 4; ++reg) {
                    int ml = t * 16 + q * 4 + reg;
                    float v = acc[t][u][reg]
                            + Red[ml * 64 + nh * 32 + u * 16 + r];
                    float x = relu_f(v + bw);
                    _Float16 hi = (_Float16)x;
                    size_t o = (size_t)(bm0 + ml) * EMBED + col;
                    Cp[o] = hi;
                    Cp[o + hoff] = (_Float16)(x - (float)hi);
                }
            }
    }
}

// ---------------------------------------------------------------------------
// Level GEMM, BN=128 (h=1). Same structure as gemm_lvl; each wave covers a
// 64-col half (u=0..3). A staging identical. Cross-slice reduce runs in TWO
// passes through the same 16KB Red so LDS stays 48KB (3 blocks/CU).
__global__ __launch_bounds__(256)
void gemm_lvl128(const _Float16* __restrict__ Ap, const _Float16* __restrict__ Wp,
                 const float* __restrict__ bW,
                 _Float16* __restrict__ Cp, int hoff)
{
    __shared__ _Float16 As[16384];              // 32 KB
    __shared__ float Red[4096];                 // 16 KB, reused over 2 passes

    int tid = threadIdx.x;
    int wave = tid >> 6, lane = tid & 63;
    int q = lane >> 4, r = lane & 15;
    int slice = wave >> 1, nh = wave & 1;
    int bm0 = blockIdx.x * 64, bn0 = blockIdx.y * 128;

    const _Float16* Asrc = Ap + (size_t)(nh ? hoff : 0)
                         + (size_t)(bm0 + r) * 1024 + slice * 512 + q * 8;

    floatx4 acc[4][4];
#pragma unroll
    for (int t = 0; t < 4; ++t)
#pragma unroll
        for (int u = 0; u < 4; ++u) acc[t][u] = (floatx4){0.f, 0.f, 0.f, 0.f};

    for (int kc = 0; kc < 8; ++kc) {
        // ---- stage 8 slots (1 KB each): identical to gemm_lvl
#pragma unroll
        for (int t = 0; t < 4; ++t)
#pragma unroll
            for (int s2 = 0; s2 < 2; ++s2) {
                const _Float16* gp = Asrc + t * (16 * 1024) + kc * 64 + s2 * 32;
                GLDS16(gp, &As[(slice * 16 + t * 4 + s2 * 2 + nh) * 512]);
            }
        __syncthreads();

#pragma unroll
        for (int s2 = 0; s2 < 2; ++s2) {
            half8 bh[4], bl[4];
#pragma unroll
            for (int u = 0; u < 4; ++u) {
                const _Float16* pb = Wp + (size_t)(blockIdx.y * 8 + nh * 4 + u) * 16384
                                   + (size_t)(slice * 16 + kc * 2 + s2) * 512 + lane * 8;
                bh[u] = *(const half8*)pb;
                bl[u] = *(const half8*)(pb + WOFF);
            }
#pragma unroll
            for (int t = 0; t < 4; ++t) {
                half8 ah = *(const half8*)&As[(slice * 16 + t * 4 + s2 * 2 + 0) * 512 + lane * 8];
                half8 al = *(const half8*)&As[(slice * 16 + t * 4 + s2 * 2 + 1) * 512 + lane * 8];
#pragma unroll
                for (int u = 0; u < 4; ++u) {
                    acc[t][u] = MFMA16(ah, bh[u], acc[t][u]);
                    acc[t][u] = MFMA16(ah, bl[u], acc[t][u]);
                    acc[t][u] = MFMA16(al, bh[u], acc[t][u]);
                }
            }
        }
        __syncthreads();
    }

    // ---- cross-slice reduce + epilogue, two passes (u = 2p, 2p+1)
#pragma unroll
    for (int p = 0; p < 2; ++p) {
        if (slice == 1) {
#pragma unroll
            for (int t = 0; t < 4; ++t)
#pragma unroll
                for (int v = 0; v < 2; ++v)
#pragma unroll
                    for (int reg = 0; reg < 4; ++reg)
                        Red[(t * 16 + q * 4 + reg) * 64 + nh * 32 + v * 16 + r]
                            = acc[t][2 * p + v][reg];
        }
        __syncthreads();
        if (slice == 0) {
#pragma unroll
            for (int t = 0; t < 4; ++t)
#pragma unroll
                for (int v = 0; v < 2; ++v) {
                    int u = 2 * p + v;
                    int col = bn0 + nh * 64 + u * 16 + r;
                    float bw = bW[col];
#pragma unroll
                    for (int reg = 0; reg < 4; ++reg) {
                        int ml = t * 16 + q * 4 + reg;
                        float vv = acc[t][u][reg]
                                 + Red[ml * 64 + nh * 32 + v * 16 + r];
                        float x = relu_f(vv + bw);
                        _Float16 hi = (_Float16)x;
                        size_t o = (size_t)(bm0 + ml) * EMBED + col;
                        Cp[o] = hi;
                        Cp[o + hoff] = (_Float16)(x - (float)hi);
                    }
                }
        }
        __syncthreads();
    }
}

// ---------------------------------------------------------------------------
// 32x32 split-K kernel (h=3,4; M multiple of 32). grid = (M/32, 16).
__global__ __launch_bounds__(256)
void gemm_splitk32(const _Float16* __restrict__ Ap, const _Float16* __restrict__ Wp,
                   const float* __restrict__ bW,
                   _Float16* __restrict__ Cp, int hoff)
{
    __shared__ float red[4096];

    int tid = threadIdx.x;
    int wave = tid >> 6, lane = tid & 63;
    int q = lane >> 4, r = lane & 15;
    int m0 = blockIdx.x * 32, n0 = blockIdx.y * 32;

    const _Float16 *pAh[2], *pAl[2];
#pragma unroll
    for (int mi = 0; mi < 2; ++mi) {
        int m = m0 + mi * 16 + r;
        int prow = 2 * m + (wave >> 1);          // child row in prev level
        int kb = (wave & 1) * 256;               // k-offset within child
        pAh[mi] = Ap + (size_t)prow * EMBED + kb + q * 8;
        pAl[mi] = pAh[mi] + hoff;
    }
    const _Float16* pB[2];
#pragma unroll
    for (int u = 0; u < 2; ++u)
        pB[u] = Wp + (size_t)(blockIdx.y * 2 + u) * 16384
              + (size_t)(wave * 8) * 512 + lane * 8;

    floatx4 acc[2][2];
#pragma unroll
    for (int mi = 0; mi < 2; ++mi)
#pragma unroll
        for (int u = 0; u < 2; ++u) acc[mi][u] = (floatx4){0.f, 0.f, 0.f, 0.f};

#pragma unroll
    for (int s = 0; s < 8; ++s) {
        half8 ah[2], al[2], bh[2], bl[2];
#pragma unroll
        for (int mi = 0; mi < 2; ++mi) {
            ah[mi] = *(const half8*)(pAh[mi] + s * 32);
            al[mi] = *(const half8*)(pAl[mi] + s * 32);
        }
#pragma unroll
        for (int u = 0; u < 2; ++u) {
            bh[u] = *(const half8*)(pB[u] + s * 512);
            bl[u] = *(const half8*)(pB[u] + s * 512 + WOFF);
        }
#pragma unroll
        for (int mi = 0; mi < 2; ++mi)
#pragma unroll
            for (int u = 0; u < 2; ++u) {
                acc[mi][u] = MFMA16(ah[mi], bh[u], acc[mi][u]);
                acc[mi][u] = MFMA16(ah[mi], bl[u], acc[mi][u]);
                acc[mi][u] = MFMA16(al[mi], bh[u], acc[mi][u]);
            }
    }

#pragma unroll
    for (int mi = 0; mi < 2; ++mi)
#pragma unroll
        for (int u = 0; u < 2; ++u)
#pragma unroll
            for (int reg = 0; reg < 4; ++reg)
                red[wave * 1024 + (mi * 16 + q * 4 + reg) * 32 + u * 16 + r]
                    = acc[mi][u][reg];
    __syncthreads();

    int row = tid >> 3, c4 = (tid & 7) * 4;
    _Float16 hi4[4], lo4[4];
#pragma unroll
    for (int j = 0; j < 4; ++j) {
        int c = row * 32 + c4 + j;
        float v = red[c] + red[1024 + c] + red[2048 + c] + red[3072 + c];
        float x = relu_f(v + bW[n0 + c4 + j]);
        _Float16 hi = (_Float16)x;
        hi4[j] = hi;
        lo4[j] = (_Float16)(x - (float)hi);
    }
    size_t o = (size_t)(m0 + row) * EMBED + n0 + c4;
#pragma unroll
    for (int j = 0; j < 4; ++j) { Cp[o + j] = hi4[j]; Cp[o + hoff + j] = lo4[j]; }
}

// ---------------------------------------------------------------------------
// 16x16 split-K kernel (h=5..13). grid = (ceil(M/16), 32).
__global__ __launch_bounds__(256)
void gemm_splitk(const _Float16* __restrict__ Ap, const _Float16* __restrict__ Wp,
                 const float* __restrict__ bW,
                 _Float16* __restrict__ Cp, int hoff, int M)
{
    __shared__ float red[1024];

    int tid = threadIdx.x;
    int wave = tid >> 6, lane = tid & 63;
    int q = lane >> 4, r = lane & 15;
    int mt = blockIdx.x, u = blockIdx.y;

    int m = mt * 16 + r;
    if (m >= M) m = M - 1;
    int prow = 2 * m + (wave >> 1);
    int kb = (wave & 1) * 256;
    const _Float16* pAh = Ap + (size_t)prow * EMBED + kb + q * 8;
    const _Float16* pAl = pAh + hoff;
    const _Float16* pB  = Wp + (size_t)u * 16384 + (size_t)(wave * 8) * 512 + lane * 8;

    floatx4 acc = (floatx4){0.f, 0.f, 0.f, 0.f};
#pragma unroll
    for (int s = 0; s < 8; ++s) {
        half8 ah = *(const half8*)(pAh + s * 32);
        half8 al = *(const half8*)(pAl + s * 32);
        half8 bh = *(const half8*)(pB + s * 512);
        half8 bl = *(const half8*)(pB + s * 512 + WOFF);
        acc = MFMA16(ah, bh, acc);
        acc = MFMA16(ah, bl, acc);
        acc = MFMA16(al, bh, acc);
    }
#pragma unroll
    for (int reg = 0; reg < 4; ++reg)
        red[wave * 256 + (q * 4 + reg) * 16 + r] = acc[reg];
    __syncthreads();

    int row = tid >> 4, col = tid & 15;
    float v = red[row * 16 + col] + red[256 + row * 16 + col]
            + red[512 + row * 16 + col] + red[768 + row * 16 + col];
    int mm = mt * 16 + row;
    if (mm < M) {
        int colg = u * 16 + col;
        float x = relu_f(v + bW[colg]);
        _Float16 hi = (_Float16)x;
        size_t o = (size_t)mm * EMBED + colg;
        Cp[o] = hi;
        Cp[o + hoff] = (_Float16)(x - (float)hi);
    }
}

// ---------------------------------------------------------------------------
// Projection: buffer row j (level-major) -> out[idx(h,m)]. Level decode:
// h = 13 - floor(log2(16383 - j)), m = j - (16384 - 2^(14-h)).
__global__ __launch_bounds__(256)
void out_kernel(const _Float16* __restrict__ Hh, const _Float16* __restrict__ Hl,
                const float* __restrict__ P, const float* __restrict__ bP,
                float* __restrict__ out, int nNodes)
{
    int t = blockIdx.x * 256 + threadIdx.x;
    int j = t >> 6, lane = t & 63;
    if (j >= nNodes) return;
    int v = nNodes - j;                         // 16383 - j >= 1
    int h = 13 - (31 - __clz(v));
    int m = j - ((nNodes + 1) - (1 << (13 - h + 1)));
    int node = ((m + 1) << (h + 1)) - 2 - __popc(m);

    half8 hv = *(const half8*)(Hh + (size_t)j * EMBED + lane * 8);
    half8 lv = *(const half8*)(Hl + (size_t)j * EMBED + lane * 8);
    float hx[8];
#pragma unroll
    for (int k = 0; k < 8; ++k) hx[k] = (float)hv[k] + (float)lv[k];
    float s[5];
#pragma unroll
    for (int c = 0; c < 5; ++c) {
        const float* p = P + c * EMBED + lane * 8;
        float4 p0 = *(const float4*)p;
        float4 p1 = *(const float4*)(p + 4);
        s[c] = hx[0] * p0.x + hx[1] * p0.y + hx[2] * p0.z + hx[3] * p0.w
             + hx[4] * p1.x + hx[5] * p1.y + hx[6] * p1.z + hx[7] * p1.w;
    }
#pragma unroll
    for (int o = 32; o > 0; o >>= 1)
#pragma unroll
        for (int c = 0; c < 5; ++c)
            s[c] += __shfl_down(s[c], o, 64);
    if (lane == 0) {
#pragma unroll
        for (int c = 0; c < 5; ++c)
            out[(size_t)node * 5 + c] = s[c] + bP[c];
    }
}

// ---------------------------------------------------------------------------
extern "C" void kernel_launch(void* const* d_in, const int* in_sizes, int n_in,
                              void* d_out, int out_size, void* d_ws, size_t ws_size,
                              hipStream_t stream)
{
    const int*   word = (const int*)d_in[1];
    const float* emb  = (const float*)d_in[4];
    const float* W    = (const float*)d_in[5];
    const float* bW   = (const float*)d_in[6];
    const float* P    = (const float*)d_in[7];
    const float* bP   = (const float*)d_in[8];
    float* out = (float*)d_out;

    int nNodes  = in_sizes[0];            // 16383
    int nLeaves = (nNodes + 1) / 2;       // 8192
    int nRows   = nNodes + 1;             // 16384

    int hoff = nRows * EMBED;             // halves between Hh and Hl
    _Float16* Hh  = (_Float16*)d_ws;
    _Float16* Hl  = Hh + hoff;
    _Float16* Whp = Hl + hoff;            // hi; lo at +WOFF

    // level row offsets: roff(h) = 16384 - 2^(14-h)
    auto roff = [&](int h) { return nRows - (1 << (14 - h)); };

    packleaf<<<dim3(256), dim3(256), 0, stream>>>(
        W, emb, word, Whp, Hh, Hl, nLeaves);

    // h=1: M=4096, BN=128 -> grid (64,4) = 256 blocks
    gemm_lvl128<<<dim3(64, 4), dim3(256), 0, stream>>>(
        Hh + (size_t)roff(0) * EMBED, Whp, bW,
        Hh + (size_t)roff(1) * EMBED, hoff);
    // h=2: M=2048, BN=64 -> grid (32,8) = 256 blocks
    gemm_lvl<<<dim3(32, 8), dim3(256), 0, stream>>>(
        Hh + (size_t)roff(1) * EMBED, Whp, bW,
        Hh + (size_t)roff(2) * EMBED, hoff);

    for (int h = 3; h <= 4; ++h) {        // M = 1024, 512
        int M = 1 << (13 - h);
        gemm_splitk32<<<dim3(M / 32, 16), dim3(256), 0, stream>>>(
            Hh + (size_t)roff(h - 1) * EMBED, Whp, bW,
            Hh + (size_t)roff(h) * EMBED, hoff);
    }
    for (int h = 5; h <= 13; ++h) {       // M = 256..1
        int M = 1 << (13 - h);
        gemm_splitk<<<dim3((M + 15) / 16, 32), dim3(256), 0, stream>>>(
            Hh + (size_t)roff(h - 1) * EMBED, Whp, bW,
            Hh + (size_t)roff(h) * EMBED, hoff, M);
    }
    out_kernel<<<dim3((nNodes * 64 + 255) / 256), dim3(256), 0, stream>>>(
        Hh, Hl, P, bP, out, nNodes);
}